// Round 3
// baseline (319.664 us; speedup 1.0000x reference)
//
#include <hip/hip_runtime.h>
#include <hip/hip_bf16.h>

#define NB   4
#define MD   2048
#define KD   2048
#define ND   2048
#define BM   128
#define BN   128
#define BK   32
#define LSTR 40   // BK + 8 pad: 80B row = 16B-aligned for ds_read_b128; 20-dword stride

typedef short bf16x8 __attribute__((ext_vector_type(8)));
typedef float f32x4  __attribute__((ext_vector_type(4)));

// pack two fp32 -> one dword of 2 bf16 (RNE)
__device__ __forceinline__ unsigned pk2(float lo, float hi) {
    union { __hip_bfloat162 h2; unsigned u; } c;
    c.h2 = __float22bfloat162_rn(make_float2(lo, hi));
    return c.u;
}

__global__ __launch_bounds__(256, 4) void SparseMatmul_kernel(
    const float* __restrict__ A, const float* __restrict__ Bmat,
    float* __restrict__ C)
{
    // double-buffered: 2 x (128*40 + 128*40) shorts = 40 KB -> 4 blocks/CU
    __shared__ unsigned short As[2][BM][LSTR];   // [m][k], k contiguous
    __shared__ unsigned short Bs[2][BN][LSTR];   // [n][k], k contiguous (transposed)

    const int tid   = threadIdx.x;
    const int batch = blockIdx.z;
    const int row0  = blockIdx.y * BM;
    const int col0  = blockIdx.x * BN;

    const float* Abase = A    + (size_t)batch * MD * KD + (size_t)row0 * KD;
    const float* Bbase = Bmat + (size_t)batch * KD * ND + col0;
    float*       Cbase = C    + (size_t)batch * MD * ND + (size_t)row0 * ND + col0;

    // A staging: 8 threads per row, float4 each, 4 row-groups
    const int a_row = tid >> 3;          // 0..31, +32 per i
    const int a_kc  = (tid & 7) * 4;     // k offset within BK
    // B staging: thread owns column n, 16 consecutive k
    const int b_n   = tid & 127;
    const int b_kh  = (tid >> 7) * 16;
    const float* Bcol = Bbase + b_n;

    const int wave = tid >> 6;
    const int lane = tid & 63;
    const int q    = lane >> 4;
    const int r    = lane & 15;
    const int wm   = (wave >> 1) * 64;
    const int wn   = (wave & 1)  * 64;

    f32x4 acc[4][4];
    #pragma unroll
    for (int i = 0; i < 4; ++i)
        #pragma unroll
        for (int j = 0; j < 4; ++j)
            acc[i][j] = (f32x4){0.f, 0.f, 0.f, 0.f};

    float4 aR[4];     // prefetch registers (raw fp32; cvt deferred so loads stay in flight)
    float  bR[16];

    auto load_tile = [&](int k0) {
        #pragma unroll
        for (int i = 0; i < 4; ++i)
            aR[i] = *(const float4*)(Abase + (size_t)(a_row + i * 32) * KD + k0 + a_kc);
        #pragma unroll
        for (int j = 0; j < 16; ++j)
            bR[j] = Bcol[(size_t)(k0 + b_kh + j) * ND];   // coalesced per wave
    };
    auto store_tile = [&](int buf) {
        #pragma unroll
        for (int i = 0; i < 4; ++i) {
            uint2 w;
            w.x = pk2(aR[i].x, aR[i].y);
            w.y = pk2(aR[i].z, aR[i].w);
            *(uint2*)&As[buf][a_row + i * 32][a_kc] = w;   // ds_write_b64
        }
        #pragma unroll
        for (int h = 0; h < 2; ++h) {
            uint4 w;
            w.x = pk2(bR[h * 8 + 0], bR[h * 8 + 1]);
            w.y = pk2(bR[h * 8 + 2], bR[h * 8 + 3]);
            w.z = pk2(bR[h * 8 + 4], bR[h * 8 + 5]);
            w.w = pk2(bR[h * 8 + 6], bR[h * 8 + 7]);
            *(uint4*)&Bs[buf][b_n][b_kh + h * 8] = w;      // ds_write_b128, 16B-aligned
        }
    };

    // prologue: tile 0 -> regs -> LDS buf 0
    load_tile(0);
    store_tile(0);

    const int NT = KD / BK;   // 64
    for (int kt = 0; kt < NT; ++kt) {
        __syncthreads();                 // one barrier per iteration
        const int cur = kt & 1;

        if (kt + 1 < NT) load_tile((kt + 1) * BK);   // in flight across MFMA section

        // frag reads + MFMA from buf[cur]; stream A-frags to cap live registers
        bf16x8 b_frag[4];
        #pragma unroll
        for (int in = 0; in < 4; ++in)
            b_frag[in] = *(const bf16x8*)&Bs[cur][wn + in * 16 + r][q * 8];  // ds_read_b128
        #pragma unroll
        for (int im = 0; im < 4; ++im) {
            const bf16x8 a_frag = *(const bf16x8*)&As[cur][wm + im * 16 + r][q * 8];
            #pragma unroll
            for (int in = 0; in < 4; ++in)
                acc[im][in] = __builtin_amdgcn_mfma_f32_16x16x32_bf16(
                    a_frag, b_frag[in], acc[im][in], 0, 0, 0);
        }

        if (kt + 1 < NT) store_tile(cur ^ 1);   // writes other buffer; no barrier needed here
    }

    // epilogue: C/D layout col=lane&15, row=quad*4+reg (m89-verified)
    #pragma unroll
    for (int im = 0; im < 4; ++im)
        #pragma unroll
        for (int in = 0; in < 4; ++in)
            #pragma unroll
            for (int j = 0; j < 4; ++j) {
                const int row = wm + im * 16 + q * 4 + j;
                const int col = wn + in * 16 + r;
                Cbase[(size_t)row * ND + col] = acc[im][in][j];
            }
}

extern "C" void kernel_launch(void* const* d_in, const int* in_sizes, int n_in,
                              void* d_out, int out_size, void* d_ws, size_t ws_size,
                              hipStream_t stream) {
    const float* a = (const float*)d_in[0];
    const float* b = (const float*)d_in[1];
    float* out = (float*)d_out;
    dim3 grid(ND / BN, MD / BM, NB);   // 16 x 16 x 4 = 1024 blocks -> 4/CU
    SparseMatmul_kernel<<<grid, dim3(256), 0, stream>>>(a, b, out);
}

// Round 4
// 248.706 us; speedup vs baseline: 1.2853x; 1.2853x over previous
//
#include <hip/hip_runtime.h>
#include <hip/hip_bf16.h>

#define NB   4
#define MD   2048
#define KD   2048
#define ND   2048
#define BM   128
#define BN   128
#define BK   32

typedef short bf16x8 __attribute__((ext_vector_type(8)));
typedef float f32x4  __attribute__((ext_vector_type(4)));
typedef unsigned int u32;

// pack two fp32 -> one dword of 2 bf16 (RNE)
__device__ __forceinline__ unsigned pk2(float lo, float hi) {
    union { __hip_bfloat162 h2; unsigned u; } c;
    c.h2 = __float22bfloat162_rn(make_float2(lo, hi));
    return c.u;
}

__device__ __forceinline__ void gload_lds16(const void* g, void* l) {
    __builtin_amdgcn_global_load_lds(
        (const __attribute__((address_space(1))) u32*)g,
        (__attribute__((address_space(3))) u32*)l,
        16, 0, 0);
}

// ---------------- Phase 1a: A fp32 -> bf16 (same layout) ----------------
__global__ __launch_bounds__(256) void cast_a_kernel(
    const float* __restrict__ A, unsigned short* __restrict__ Abf)
{
    const size_t idx = (size_t)blockIdx.x * 256 + threadIdx.x;   // float4 index
    const float4 v = ((const float4*)A)[idx];
    uint2 w;
    w.x = pk2(v.x, v.y);
    w.y = pk2(v.z, v.w);
    ((uint2*)Abf)[idx] = w;
}

// ------- Phase 1b: B[b][k][n] fp32 -> BT[b][n][k] bf16 (64x64 LDS tiles) -------
__global__ __launch_bounds__(256) void transpose_b_kernel(
    const float* __restrict__ B, unsigned short* __restrict__ BT)
{
    __shared__ float t[64][65];   // +1 pad: both phases <=2-way conflicts (free)
    const int tid = threadIdx.x;
    const int b   = blockIdx.z;
    const int k0  = blockIdx.x * 64;
    const int n0  = blockIdx.y * 64;

    const float* Bb = B + (size_t)b * KD * ND;
    // read: 4 passes, float4 per thread, coalesced
    const int rk = tid >> 4;          // 0..15, +16/pass
    const int rn = (tid & 15) * 4;
    #pragma unroll
    for (int p = 0; p < 4; ++p) {
        const int kl = p * 16 + rk;
        const float4 v = *(const float4*)(Bb + (size_t)(k0 + kl) * ND + n0 + rn);
        t[kl][rn + 0] = v.x; t[kl][rn + 1] = v.y;
        t[kl][rn + 2] = v.z; t[kl][rn + 3] = v.w;
    }
    __syncthreads();
    // write: thread owns column n, 16 consecutive k; 2x uint4 (32B) stores
    const int wn = tid >> 2;          // 0..63
    const int wk = (tid & 3) * 16;
    float f[16];
    #pragma unroll
    for (int j = 0; j < 16; ++j) f[j] = t[wk + j][wn];   // (k+n)%32 banks: 2-way, free
    uint4 w0, w1;
    w0.x = pk2(f[0], f[1]);  w0.y = pk2(f[2], f[3]);
    w0.z = pk2(f[4], f[5]);  w0.w = pk2(f[6], f[7]);
    w1.x = pk2(f[8], f[9]);  w1.y = pk2(f[10], f[11]);
    w1.z = pk2(f[12], f[13]); w1.w = pk2(f[14], f[15]);
    unsigned short* dst = BT + (size_t)b * ND * KD + (size_t)(n0 + wn) * KD + k0 + wk;
    *(uint4*)(dst) = w0;
    *(uint4*)(dst + 8) = w1;
}

// ---------------- Phase 2: bf16 gemm_bt, global_load_lds (m97 structure) ----------------
__global__ __launch_bounds__(256, 4) void gemm_bt_kernel(
    const unsigned short* __restrict__ Abf, const unsigned short* __restrict__ BT,
    float* __restrict__ C)
{
    // unpadded [row][32] bf16: 64B rows -> global_load_lds contiguous constraint;
    // frag ds_read_b128 bank group = 16*(r%2)+4q -> all 32 banks, minimum phases
    __shared__ unsigned short As[BM * BK];   // 8 KB
    __shared__ unsigned short Bs[BN * BK];   // 8 KB

    const int tid   = threadIdx.x;
    const int batch = blockIdx.z;
    const int row0  = blockIdx.y * BM;
    const int col0  = blockIdx.x * BN;

    const unsigned short* Abase = Abf + (size_t)batch * MD * KD + (size_t)row0 * KD;
    const unsigned short* Bbase = BT  + (size_t)batch * ND * KD + (size_t)col0 * KD;
    float*                Cbase = C   + (size_t)batch * MD * ND + (size_t)row0 * ND + col0;

    const int wave = tid >> 6;
    const int lane = tid & 63;
    const int q    = lane >> 4;
    const int r    = lane & 15;
    const int wm   = (wave >> 1) * 64;
    const int wn   = (wave & 1)  * 64;

    // staging coords: per GLDS instr a wave covers 16 rows x 64B; lds dest = base + lane*16
    const int s_row = tid >> 2;        // 0..63 (+64 for i=1)
    const int s_kc  = (tid & 3) * 8;   // bf16 offset within row

    f32x4 acc[4][4];
    #pragma unroll
    for (int i = 0; i < 4; ++i)
        #pragma unroll
        for (int j = 0; j < 4; ++j)
            acc[i][j] = (f32x4){0.f, 0.f, 0.f, 0.f};

    for (int k0 = 0; k0 < KD; k0 += BK) {
        #pragma unroll
        for (int i = 0; i < 2; ++i) {
            const int row = s_row + i * 64;
            gload_lds16(Abase + (size_t)row * KD + k0 + s_kc, As + i * 64 * BK + wave * 512);
            gload_lds16(Bbase + (size_t)row * KD + k0 + s_kc, Bs + i * 64 * BK + wave * 512);
        }
        __syncthreads();   // drains vmcnt -> tiles visible

        bf16x8 b_frag[4];
        #pragma unroll
        for (int in = 0; in < 4; ++in)
            b_frag[in] = *(const bf16x8*)&Bs[(wn + in * 16 + r) * BK + q * 8];
        #pragma unroll
        for (int im = 0; im < 4; ++im) {
            const bf16x8 a_frag = *(const bf16x8*)&As[(wm + im * 16 + r) * BK + q * 8];
            #pragma unroll
            for (int in = 0; in < 4; ++in)
                acc[im][in] = __builtin_amdgcn_mfma_f32_16x16x32_bf16(
                    a_frag, b_frag[in], acc[im][in], 0, 0, 0);
        }
        __syncthreads();   // before next overwrite
    }

    // epilogue: C/D layout col=lane&15, row=quad*4+reg (m89-verified)
    #pragma unroll
    for (int im = 0; im < 4; ++im)
        #pragma unroll
        for (int in = 0; in < 4; ++in)
            #pragma unroll
            for (int j = 0; j < 4; ++j) {
                const int row = wm + im * 16 + q * 4 + j;
                const int col = wn + in * 16 + r;
                Cbase[(size_t)row * ND + col] = acc[im][in][j];
            }
}

// ---------------- Fallback (ws too small): R2 fused kernel ----------------
#define LSTR 40
__global__ __launch_bounds__(256, 4) void fused_kernel(
    const float* __restrict__ A, const float* __restrict__ Bmat,
    float* __restrict__ C)
{
    __shared__ unsigned short As[BM][LSTR];
    __shared__ unsigned short Bs[BN][LSTR];
    const int tid   = threadIdx.x;
    const int batch = blockIdx.z;
    const int row0  = blockIdx.y * BM;
    const int col0  = blockIdx.x * BN;
    const float* Abase = A    + (size_t)batch * MD * KD + (size_t)row0 * KD;
    const float* Bbase = Bmat + (size_t)batch * KD * ND + col0;
    float*       Cbase = C    + (size_t)batch * MD * ND + (size_t)row0 * ND + col0;
    const int a_row = tid >> 3, a_kc = (tid & 7) * 4;
    const int b_n = tid & 127, b_kh = (tid >> 7) * 16;
    const float* Bcol = Bbase + b_n;
    const int wave = tid >> 6, lane = tid & 63, q = lane >> 4, r = lane & 15;
    const int wm = (wave >> 1) * 64, wn = (wave & 1) * 64;
    f32x4 acc[4][4];
    #pragma unroll
    for (int i = 0; i < 4; ++i)
        #pragma unroll
        for (int j = 0; j < 4; ++j) acc[i][j] = (f32x4){0.f, 0.f, 0.f, 0.f};
    for (int k0 = 0; k0 < KD; k0 += BK) {
        #pragma unroll
        for (int i = 0; i < 4; ++i) {
            const int row = a_row + i * 32;
            const float4 v = *(const float4*)(Abase + (size_t)row * KD + k0 + a_kc);
            uint2 w; w.x = pk2(v.x, v.y); w.y = pk2(v.z, v.w);
            *(uint2*)&As[row][a_kc] = w;
        }
        #pragma unroll
        for (int h = 0; h < 2; ++h) {
            const int kb = b_kh + h * 8;
            float bv[8];
            #pragma unroll
            for (int j = 0; j < 8; ++j) bv[j] = Bcol[(size_t)(k0 + kb + j) * ND];
            uint4 w;
            w.x = pk2(bv[0], bv[1]); w.y = pk2(bv[2], bv[3]);
            w.z = pk2(bv[4], bv[5]); w.w = pk2(bv[6], bv[7]);
            *(uint4*)&Bs[b_n][kb] = w;
        }
        __syncthreads();
        bf16x8 a_frag[4], b_frag[4];
        #pragma unroll
        for (int im = 0; im < 4; ++im)
            a_frag[im] = *(const bf16x8*)&As[wm + im * 16 + r][q * 8];
        #pragma unroll
        for (int in = 0; in < 4; ++in)
            b_frag[in] = *(const bf16x8*)&Bs[wn + in * 16 + r][q * 8];
        #pragma unroll
        for (int im = 0; im < 4; ++im)
            #pragma unroll
            for (int in = 0; in < 4; ++in)
                acc[im][in] = __builtin_amdgcn_mfma_f32_16x16x32_bf16(
                    a_frag[im], b_frag[in], acc[im][in], 0, 0, 0);
        __syncthreads();
    }
    #pragma unroll
    for (int im = 0; im < 4; ++im)
        #pragma unroll
        for (int in = 0; in < 4; ++in)
            #pragma unroll
            for (int j = 0; j < 4; ++j)
                Cbase[(size_t)(wm + im * 16 + q * 4 + j) * ND + wn + in * 16 + r]
                    = acc[im][in][j];
}

extern "C" void kernel_launch(void* const* d_in, const int* in_sizes, int n_in,
                              void* d_out, int out_size, void* d_ws, size_t ws_size,
                              hipStream_t stream) {
    const float* a = (const float*)d_in[0];
    const float* b = (const float*)d_in[1];
    float* out = (float*)d_out;

    const size_t abf_bytes = (size_t)NB * MD * KD * 2;   // 32 MB
    const size_t bt_bytes  = (size_t)NB * KD * ND * 2;   // 32 MB

    if (ws_size >= abf_bytes + bt_bytes) {
        unsigned short* Abf = (unsigned short*)d_ws;
        unsigned short* BT  = (unsigned short*)((char*)d_ws + abf_bytes);
        cast_a_kernel<<<dim3((NB * MD * KD / 4) / 256), dim3(256), 0, stream>>>(a, Abf);
        transpose_b_kernel<<<dim3(KD / 64, ND / 64, NB), dim3(256), 0, stream>>>(b, BT);
        gemm_bt_kernel<<<dim3(ND / BN, MD / BM, NB), dim3(256), 0, stream>>>(Abf, BT, out);
    } else {
        fused_kernel<<<dim3(ND / BN, MD / BM, NB), dim3(256), 0, stream>>>(a, b, out);
    }
}

// Round 5
// 241.864 us; speedup vs baseline: 1.3217x; 1.0283x over previous
//
#include <hip/hip_runtime.h>
#include <hip/hip_bf16.h>

#define NB   4
#define MD   2048
#define KD   2048
#define ND   2048
#define BM   128
#define BN   128
#define BK   64   // two 32-k sub-tiles per barrier

typedef short bf16x8 __attribute__((ext_vector_type(8)));
typedef float f32x4  __attribute__((ext_vector_type(4)));
typedef unsigned int u32;

// pack two fp32 -> one dword of 2 bf16 (RNE)
__device__ __forceinline__ unsigned pk2(float lo, float hi) {
    union { __hip_bfloat162 h2; unsigned u; } c;
    c.h2 = __float22bfloat162_rn(make_float2(lo, hi));
    return c.u;
}

__device__ __forceinline__ void gload_lds16(const void* g, void* l) {
    __builtin_amdgcn_global_load_lds(
        (const __attribute__((address_space(1))) u32*)g,
        (__attribute__((address_space(3))) u32*)l,
        16, 0, 0);
}

// ---- Phase 1 (fused): A fp32->bf16 cast  +  B[b][k][n] -> BT[b][n][k] bf16 ----
#define NCAST ((NB * MD * KD / 4) / 256)   // 16384 cast blocks (float4/thread)

__global__ __launch_bounds__(256) void prep_kernel(
    const float* __restrict__ A, const float* __restrict__ B,
    unsigned short* __restrict__ Abf, unsigned short* __restrict__ BT)
{
    __shared__ float t[64][65];   // transpose tile; +1 pad -> <=2-way conflicts (free)
    const int tid = threadIdx.x;

    if (blockIdx.x < NCAST) {
        // ---- A cast: pure streaming ----
        const size_t idx = (size_t)blockIdx.x * 256 + tid;   // float4 index
        const float4 v = ((const float4*)A)[idx];
        uint2 w;
        w.x = pk2(v.x, v.y);
        w.y = pk2(v.z, v.w);
        ((uint2*)Abf)[idx] = w;
        return;
    }
    // ---- B transpose-cast: 64x64 tiles ----
    const int bx  = blockIdx.x - NCAST;      // 0..4095
    const int b   = bx >> 10;                // batch (1024 tiles per batch)
    const int rem = bx & 1023;
    const int k0  = (rem & 31) * 64;
    const int n0  = (rem >> 5) * 64;

    const float* Bb = B + (size_t)b * KD * ND;
    const int rk = tid >> 4;                 // 0..15, +16/pass
    const int rn = (tid & 15) * 4;
    #pragma unroll
    for (int p = 0; p < 4; ++p) {
        const int kl = p * 16 + rk;
        const float4 v = *(const float4*)(Bb + (size_t)(k0 + kl) * ND + n0 + rn);
        t[kl][rn + 0] = v.x; t[kl][rn + 1] = v.y;
        t[kl][rn + 2] = v.z; t[kl][rn + 3] = v.w;
    }
    __syncthreads();
    const int wn = tid >> 2;                 // 0..63 (owns column n)
    const int wk = (tid & 3) * 16;           // 16 consecutive k
    float f[16];
    #pragma unroll
    for (int j = 0; j < 16; ++j) f[j] = t[wk + j][wn];   // 2-way bank alias, free
    uint4 w0, w1;
    w0.x = pk2(f[0], f[1]);   w0.y = pk2(f[2], f[3]);
    w0.z = pk2(f[4], f[5]);   w0.w = pk2(f[6], f[7]);
    w1.x = pk2(f[8], f[9]);   w1.y = pk2(f[10], f[11]);
    w1.z = pk2(f[12], f[13]); w1.w = pk2(f[14], f[15]);
    unsigned short* dst = BT + (size_t)b * ND * KD + (size_t)(n0 + wn) * KD + k0 + wk;
    *(uint4*)(dst) = w0;
    *(uint4*)(dst + 8) = w1;
}

// ---- Phase 2: bf16 gemm_bt, BK=64 as two 32-k sub-tiles (32 MFMA per barrier) ----
__global__ __launch_bounds__(256, 4) void gemm_bt_kernel(
    const unsigned short* __restrict__ Abf, const unsigned short* __restrict__ BT,
    float* __restrict__ C)
{
    // [kh][row][32]: 64-B rows keep the conflict-minimal frag ds_read_b128 pattern
    // AND satisfy global_load_lds' lane-contiguous destination constraint.
    __shared__ unsigned short As[2][BM][32];   // 16 KB
    __shared__ unsigned short Bs[2][BN][32];   // 16 KB  -> 32 KB total, 4 blocks/CU

    const int tid   = threadIdx.x;
    const int batch = blockIdx.z;
    const int row0  = blockIdx.y * BM;
    const int col0  = blockIdx.x * BN;

    const unsigned short* Abase = Abf + (size_t)batch * MD * KD + (size_t)row0 * KD;
    const unsigned short* Bbase = BT  + (size_t)batch * ND * KD + (size_t)col0 * KD;
    float*                Cbase = C   + (size_t)batch * MD * ND + (size_t)row0 * ND + col0;

    const int wave = tid >> 6;
    const int lane = tid & 63;
    const int q    = lane >> 4;
    const int r    = lane & 15;
    const int wm   = (wave >> 1) * 64;
    const int wn   = (wave & 1)  * 64;

    // staging: per GLDS a wave covers 16 rows x 64 B; lds dest = base + lane*16
    const int s_row = tid >> 2;        // 0..63 (+64 for i=1)
    const int s_kc  = (tid & 3) * 8;   // bf16 offset within 32-k row

    f32x4 acc[4][4];
    #pragma unroll
    for (int i = 0; i < 4; ++i)
        #pragma unroll
        for (int j = 0; j < 4; ++j)
            acc[i][j] = (f32x4){0.f, 0.f, 0.f, 0.f};

    for (int k0 = 0; k0 < KD; k0 += BK) {   // 32 iterations
        #pragma unroll
        for (int kh = 0; kh < 2; ++kh) {
            const int kg = k0 + kh * 32;
            #pragma unroll
            for (int i = 0; i < 2; ++i) {
                const int row = s_row + i * 64;
                unsigned short* la = &As[kh][0][0] + i * 64 * 32 + wave * 512;
                unsigned short* lb = &Bs[kh][0][0] + i * 64 * 32 + wave * 512;
                gload_lds16(Abase + (size_t)row * KD + kg + s_kc, la);
                gload_lds16(Bbase + (size_t)row * KD + kg + s_kc, lb);
            }
        }
        __syncthreads();   // one drain per 64-k

        #pragma unroll
        for (int kh = 0; kh < 2; ++kh) {
            bf16x8 b_frag[4];
            #pragma unroll
            for (int in = 0; in < 4; ++in)
                b_frag[in] = *(const bf16x8*)&Bs[kh][wn + in * 16 + r][q * 8];
            #pragma unroll
            for (int im = 0; im < 4; ++im) {
                const bf16x8 a_frag = *(const bf16x8*)&As[kh][wm + im * 16 + r][q * 8];
                #pragma unroll
                for (int in = 0; in < 4; ++in)
                    acc[im][in] = __builtin_amdgcn_mfma_f32_16x16x32_bf16(
                        a_frag, b_frag[in], acc[im][in], 0, 0, 0);
            }
        }
        __syncthreads();
    }

    // epilogue: C/D layout col=lane&15, row=quad*4+reg (m89-verified)
    #pragma unroll
    for (int im = 0; im < 4; ++im)
        #pragma unroll
        for (int in = 0; in < 4; ++in)
            #pragma unroll
            for (int j = 0; j < 4; ++j) {
                const int row = wm + im * 16 + q * 4 + j;
                const int col = wn + in * 16 + r;
                Cbase[(size_t)row * ND + col] = acc[im][in][j];
            }
}

// ---- Fallback (ws too small): R2 fused fp32-staging kernel ----
#define LSTR 40
__global__ __launch_bounds__(256, 4) void fused_kernel(
    const float* __restrict__ A, const float* __restrict__ Bmat,
    float* __restrict__ C)
{
    __shared__ unsigned short Asf[BM][LSTR];
    __shared__ unsigned short Bsf[BN][LSTR];
    const int tid   = threadIdx.x;
    const int batch = blockIdx.z;
    const int row0  = blockIdx.y * BM;
    const int col0  = blockIdx.x * BN;
    const float* Abase = A    + (size_t)batch * MD * KD + (size_t)row0 * KD;
    const float* Bbase = Bmat + (size_t)batch * KD * ND + col0;
    float*       Cbase = C    + (size_t)batch * MD * ND + (size_t)row0 * ND + col0;
    const int a_row = tid >> 3, a_kc = (tid & 7) * 4;
    const int b_n = tid & 127, b_kh = (tid >> 7) * 16;
    const float* Bcol = Bbase + b_n;
    const int wave = tid >> 6, lane = tid & 63, q = lane >> 4, r = lane & 15;
    const int wm = (wave >> 1) * 64, wn = (wave & 1) * 64;
    f32x4 acc[4][4];
    #pragma unroll
    for (int i = 0; i < 4; ++i)
        #pragma unroll
        for (int j = 0; j < 4; ++j) acc[i][j] = (f32x4){0.f, 0.f, 0.f, 0.f};
    for (int k0 = 0; k0 < KD; k0 += 32) {
        #pragma unroll
        for (int i = 0; i < 4; ++i) {
            const int row = a_row + i * 32;
            const float4 v = *(const float4*)(Abase + (size_t)row * KD + k0 + a_kc);
            uint2 w; w.x = pk2(v.x, v.y); w.y = pk2(v.z, v.w);
            *(uint2*)&Asf[row][a_kc] = w;
        }
        #pragma unroll
        for (int h = 0; h < 2; ++h) {
            const int kb = b_kh + h * 8;
            float bv[8];
            #pragma unroll
            for (int j = 0; j < 8; ++j) bv[j] = Bcol[(size_t)(k0 + kb + j) * ND];
            uint4 w;
            w.x = pk2(bv[0], bv[1]); w.y = pk2(bv[2], bv[3]);
            w.z = pk2(bv[4], bv[5]); w.w = pk2(bv[6], bv[7]);
            *(uint4*)&Bsf[b_n][kb] = w;
        }
        __syncthreads();
        bf16x8 a_frag[4], b_frag[4];
        #pragma unroll
        for (int im = 0; im < 4; ++im)
            a_frag[im] = *(const bf16x8*)&Asf[wm + im * 16 + r][q * 8];
        #pragma unroll
        for (int in = 0; in < 4; ++in)
            b_frag[in] = *(const bf16x8*)&Bsf[wn + in * 16 + r][q * 8];
        #pragma unroll
        for (int im = 0; im < 4; ++im)
            #pragma unroll
            for (int in = 0; in < 4; ++in)
                acc[im][in] = __builtin_amdgcn_mfma_f32_16x16x32_bf16(
                    a_frag[im], b_frag[in], acc[im][in], 0, 0, 0);
        __syncthreads();
    }
    #pragma unroll
    for (int im = 0; im < 4; ++im)
        #pragma unroll
        for (int in = 0; in < 4; ++in)
            #pragma unroll
            for (int j = 0; j < 4; ++j)
                Cbase[(size_t)(wm + im * 16 + q * 4 + j) * ND + wn + in * 16 + r]
                    = acc[im][in][j];
}

extern "C" void kernel_launch(void* const* d_in, const int* in_sizes, int n_in,
                              void* d_out, int out_size, void* d_ws, size_t ws_size,
                              hipStream_t stream) {
    const float* a = (const float*)d_in[0];
    const float* b = (const float*)d_in[1];
    float* out = (float*)d_out;

    const size_t abf_bytes = (size_t)NB * MD * KD * 2;   // 32 MB
    const size_t bt_bytes  = (size_t)NB * KD * ND * 2;   // 32 MB

    if (ws_size >= abf_bytes + bt_bytes) {
        unsigned short* Abf = (unsigned short*)d_ws;
        unsigned short* BT  = (unsigned short*)((char*)d_ws + abf_bytes);
        prep_kernel<<<dim3(NCAST + NB * (KD / 64) * (ND / 64)), dim3(256), 0, stream>>>(
            a, b, Abf, BT);
        gemm_bt_kernel<<<dim3(ND / BN, MD / BM, NB), dim3(256), 0, stream>>>(Abf, BT, out);
    } else {
        fused_kernel<<<dim3(ND / BN, MD / BM, NB), dim3(256), 0, stream>>>(a, b, out);
    }
}